// Round 4
// baseline (104516.675 us; speedup 1.0000x reference)
//
#include <hip/hip_runtime.h>

typedef __attribute__((ext_vector_type(8))) short short8;
typedef __attribute__((ext_vector_type(4))) float f32x4;

#define SEQ 4096
#define HID 2048
#define G4  8192
#define NBLK 256
#define FSTR 16   // flag stride in u32 (64 B) -> no RMW, low false sharing

static __device__ __forceinline__ ushort f2bf(float f) {
    unsigned u = __float_as_uint(f);
    u = (u + 0x7fffu + ((u >> 16) & 1u)) >> 16;   // RNE
    return (ushort)u;
}

// ---------------- f32 -> bf16 conversion (vectorized, 4 elems/thread) ----------
__global__ void __launch_bounds__(256) k_f32_to_bf16(const float* __restrict__ in,
                                                     ushort* __restrict__ out, int n4) {
    int i = blockIdx.x * blockDim.x + threadIdx.x;
    if (i < n4) {
        float4 v = ((const float4*)in)[i];
        ushort4 o;
        o.x = f2bf(v.x); o.y = f2bf(v.y); o.z = f2bf(v.z); o.w = f2bf(v.w);
        ((ushort4*)out)[i] = o;
    }
}

// ---------------- xg = x @ W_ih^T + (b_ih + b_hh), bf16 MFMA, 128x128 tile ------
__global__ void __launch_bounds__(256) k_gemm_xg(
    const ushort* __restrict__ A, const ushort* __restrict__ B,
    const float* __restrict__ bih, const float* __restrict__ bhh,
    float* __restrict__ C)
{
    __shared__ ushort Asm[128 * 40];
    __shared__ ushort Bsm[128 * 40];
    const int tid = threadIdx.x;
    const int brow = blockIdx.y * 128;
    const int bcol = blockIdx.x * 128;
    const int w = tid >> 6, l = tid & 63;
    const int wm = w >> 1, wn = w & 1;

    f32x4 acc[4][4] = {};

    for (int k0 = 0; k0 < 2048; k0 += 32) {
        __syncthreads();
        #pragma unroll
        for (int i = 0; i < 2; ++i) {
            int q = tid + i * 256;
            int r = q >> 2, kc = q & 3;
            *(uint4*)((char*)Asm + r * 80 + kc * 16) =
                *(const uint4*)(A + (size_t)(brow + r) * 2048 + k0 + kc * 8);
            *(uint4*)((char*)Bsm + r * 80 + kc * 16) =
                *(const uint4*)(B + (size_t)(bcol + r) * 2048 + k0 + kc * 8);
        }
        __syncthreads();

        short8 af[4], bf[4];
        #pragma unroll
        for (int m = 0; m < 4; ++m)
            af[m] = *(const short8*)((char*)Asm + (wm * 64 + m * 16 + (l & 15)) * 80 + (l >> 4) * 16);
        #pragma unroll
        for (int n = 0; n < 4; ++n)
            bf[n] = *(const short8*)((char*)Bsm + (wn * 64 + n * 16 + (l & 15)) * 80 + (l >> 4) * 16);

        #pragma unroll
        for (int m = 0; m < 4; ++m)
            #pragma unroll
            for (int n = 0; n < 4; ++n)
                acc[m][n] = __builtin_amdgcn_mfma_f32_16x16x32_bf16(af[m], bf[n], acc[m][n], 0, 0, 0);
    }

    const int lr = (l >> 4) * 4, lc = l & 15;
    #pragma unroll
    for (int m = 0; m < 4; ++m)
        #pragma unroll
        for (int n = 0; n < 4; ++n) {
            int col = bcol + wn * 64 + n * 16 + lc;
            float bsum = bih[col] + bhh[col];
            #pragma unroll
            for (int r = 0; r < 4; ++r) {
                int rowg = brow + wm * 64 + m * 16 + lr + r;
                C[(size_t)rowg * 8192 + col] = acc[m][n][r] + bsum;
            }
        }
}

// ---------------- persistent cooperative LSTM recurrence ------------------------
// EXACT Round-1 structure (proven pass) with ONE change: the single global
// counter (serialized 256-deep release-RMW queue, ~19us/step) is replaced by
// per-block flag words. Producer: relaxed h stores -> wave-wide vmcnt(0) ->
// RELEASE flag store (256 independent lines, no RMW). Consumer: each of the
// 256 threads ACQUIRE-loads its own flag (acquire => buffer_inv, same proven
// mechanics as R1's poll) and the block agrees via __syncthreads_and.
__global__ void __launch_bounds__(256, 1) k_lstm_rec(
    const ushort* __restrict__ Whh,   // bf16 [8192][2048]
    const float* __restrict__ xg,     // [4096][8192]
    float* __restrict__ hbuf,         // [2][2048]
    unsigned* __restrict__ flags,     // [256*FSTR], zeroed before launch
    const float* __restrict__ Wlin,   // [2048]
    const float* __restrict__ blin,   // [1]
    float* __restrict__ out)          // [1]
{
    extern __shared__ char smem[];
    ushort* w_lds = (ushort*)smem;                    // 32*2048*2      = 131072 B
    float*  h_lds = (float*)(smem + 131072);          // 2080 f32 (padded) = 8320 B
    float*  g_lds = (float*)(smem + 131072 + 8320);   // 32 f32

    const int tid = threadIdx.x;
    const int b   = blockIdx.x;
    const int hbase = b * 8;

    // stage W_hh rows (once): local row r = gate*8 + kk
    for (int r = 0; r < 32; ++r) {
        int grow = ((r >> 3) << 11) + hbase + (r & 7);
        ((uint4*)(w_lds + r * 2048))[tid] = ((const uint4*)(Whh + (size_t)grow * 2048))[tid];
    }

    float c_reg = 0.0f;
    if (tid < 8)
        __hip_atomic_store(&hbuf[hbase + tid], 0.0f, __ATOMIC_RELAXED, __HIP_MEMORY_SCOPE_AGENT);
    asm volatile("s_waitcnt vmcnt(0)" ::: "memory");   // wave-wide store drain
    if (tid == 0)
        __hip_atomic_store(&flags[b * FSTR], 1u, __ATOMIC_RELEASE, __HIP_MEMORY_SCOPE_AGENT);

    const int row = tid >> 3;   // 0..31  (wave w handles gate w)
    const int cc  = tid & 7;    // col-chunk lane within row

    for (int t = 0; t < SEQ; ++t) {
        const float* hsrc = hbuf + (t & 1) * HID;
        float* hdst = hbuf + ((t + 1) & 1) * HID;

        // prefetch xg (independent of h) BEFORE the wait -> values in registers
        float xgv0 = 0.f, xgv1 = 0.f, xgv2 = 0.f, xgv3 = 0.f;
        if (tid < 8) {
            const float* xr = xg + (size_t)t * G4 + hbase + tid;
            xgv0 = xr[0]; xgv1 = xr[2048]; xgv2 = xr[4096]; xgv3 = xr[6144];
        }

        // block-wide acquire poll: thread tid owns flags[tid*FSTR]
        {
            const unsigned tgt = (unsigned)(t + 1);
            while (!__syncthreads_and((int)(
                       __hip_atomic_load(&flags[tid * FSTR], __ATOMIC_ACQUIRE,
                                         __HIP_MEMORY_SCOPE_AGENT) >= tgt)))
                __builtin_amdgcn_s_sleep(1);
        }
        // __syncthreads_and is itself the barrier; all flags >= t+1 seen

        // stage h_t into LDS (relaxed agent loads after acquire, as in R1)
        #pragma unroll
        for (int i = 0; i < 8; ++i) {
            int col = tid + (i << 8);
            float v = __hip_atomic_load(&hsrc[col], __ATOMIC_RELAXED, __HIP_MEMORY_SCOPE_AGENT);
            h_lds[col + ((col >> 8) << 2)] = v;   // +16B pad per 256 floats
        }
        __syncthreads();

        // dot: row over interleaved 8-col groups cc*8 + 64k
        float s0 = 0.f, s1 = 0.f, s2 = 0.f, s3 = 0.f;
        const ushort* wrow = w_lds + row * 2048;
        #pragma unroll 8
        for (int k = 0; k < 32; ++k) {
            int col0 = (cc << 3) + (k << 6);
            uint4 wv = *(const uint4*)(wrow + col0);
            const float* hp = h_lds + col0 + ((col0 >> 8) << 2);
            float4 ha = *(const float4*)hp;
            float4 hb = *(const float4*)(hp + 4);
            s0 += __uint_as_float(wv.x << 16)         * ha.x;
            s1 += __uint_as_float(wv.x & 0xffff0000u) * ha.y;
            s2 += __uint_as_float(wv.y << 16)         * ha.z;
            s3 += __uint_as_float(wv.y & 0xffff0000u) * ha.w;
            s0 += __uint_as_float(wv.z << 16)         * hb.x;
            s1 += __uint_as_float(wv.z & 0xffff0000u) * hb.y;
            s2 += __uint_as_float(wv.w << 16)         * hb.z;
            s3 += __uint_as_float(wv.w & 0xffff0000u) * hb.w;
        }
        float sum = (s0 + s1) + (s2 + s3);
        sum += __shfl_xor(sum, 1);
        sum += __shfl_xor(sum, 2);
        sum += __shfl_xor(sum, 4);
        if (cc == 0) g_lds[row] = sum;
        __syncthreads();

        if (tid < 8) {
            float gi = g_lds[tid]      + xgv0;
            float gf = g_lds[8 + tid]  + xgv1;
            float gg = g_lds[16 + tid] + xgv2;
            float go = g_lds[24 + tid] + xgv3;
            float si = 1.0f / (1.0f + __expf(-gi));
            float sf = 1.0f / (1.0f + __expf(-gf));
            float tg = tanhf(gg);
            float so = 1.0f / (1.0f + __expf(-go));
            c_reg = sf * c_reg + si * tg;
            float hn = so * tanhf(c_reg);
            __hip_atomic_store(&hdst[hbase + tid], hn, __ATOMIC_RELAXED, __HIP_MEMORY_SCOPE_AGENT);
        }
        asm volatile("s_waitcnt vmcnt(0)" ::: "memory");   // wave-wide drain of h stores
        if (tid == 0)
            __hip_atomic_store(&flags[b * FSTR], (unsigned)(t + 2), __ATOMIC_RELEASE,
                               __HIP_MEMORY_SCOPE_AGENT);
    }

    // final: out = sigmoid(h_last . W_lin + b_lin), block 0 only
    if (b == 0) {
        {
            const unsigned tgt = (unsigned)(SEQ + 1);
            while (!__syncthreads_and((int)(
                       __hip_atomic_load(&flags[tid * FSTR], __ATOMIC_ACQUIRE,
                                         __HIP_MEMORY_SCOPE_AGENT) >= tgt)))
                __builtin_amdgcn_s_sleep(1);
        }
        const float* hf = hbuf;   // SEQ even -> h_SEQ in slot 0
        float s = 0.f;
        #pragma unroll
        for (int i = 0; i < 8; ++i) {
            int col = tid + (i << 8);
            float v = __hip_atomic_load(&hf[col], __ATOMIC_RELAXED, __HIP_MEMORY_SCOPE_AGENT);
            s += v * Wlin[col];
        }
        #pragma unroll
        for (int o = 1; o < 64; o <<= 1) s += __shfl_xor(s, o);
        if ((tid & 63) == 0) g_lds[tid >> 6] = s;
        __syncthreads();
        if (tid == 0) {
            float tot = g_lds[0] + g_lds[1] + g_lds[2] + g_lds[3] + blin[0];
            out[0] = 1.0f / (1.0f + __expf(-tot));
        }
    }
}

extern "C" void kernel_launch(void* const* d_in, const int* in_sizes, int n_in,
                              void* d_out, int out_size, void* d_ws, size_t ws_size,
                              hipStream_t stream) {
    const float* x    = (const float*)d_in[0];   // [1][4096][2048]
    const float* Wih  = (const float*)d_in[1];   // [8192][2048]
    const float* Whh  = (const float*)d_in[2];   // [8192][2048]
    const float* bih  = (const float*)d_in[3];   // [8192]
    const float* bhh  = (const float*)d_in[4];   // [8192]
    const float* Wlin = (const float*)d_in[5];   // [1][2048]
    const float* blin = (const float*)d_in[6];   // [1]
    float* out = (float*)d_out;

    char* ws = (char*)d_ws;
    float*    xgbuf = (float*)ws;                         // 134,217,728 B
    ushort*   xbf   = (ushort*)(ws + 134217728);          //  16,777,216 B
    ushort*   wihbf = (ushort*)(ws + 150994944);          //  33,554,432 B
    ushort*   whhbf = (ushort*)(ws + 184549376);          //  33,554,432 B
    float*    hbuf  = (float*)(ws + 218103808);           //      16,384 B
    unsigned* flags = (unsigned*)(ws + 218120192);        //      16,384 B (256*FSTR*4)

    // f32 -> bf16 (x, W_ih, W_hh)
    k_f32_to_bf16<<<8192,  256, 0, stream>>>(x,   xbf,   2097152);
    k_f32_to_bf16<<<16384, 256, 0, stream>>>(Wih, wihbf, 4194304);
    k_f32_to_bf16<<<16384, 256, 0, stream>>>(Whh, whhbf, 4194304);

    // input GEMM: all timesteps' input-side gate preactivations
    k_gemm_xg<<<dim3(64, 32), 256, 0, stream>>>(xbf, wihbf, bih, bhh, xgbuf);

    // flags must start at zero every call (harness doesn't re-poison)
    hipMemsetAsync(flags, 0, NBLK * FSTR * sizeof(unsigned), stream);

    // persistent cooperative recurrence: 139,520 B dynamic LDS (as Round 1)
    hipFuncSetAttribute((const void*)k_lstm_rec,
                        hipFuncAttributeMaxDynamicSharedMemorySize, 163840);
    void* args[] = { (void*)&whhbf, (void*)&xgbuf, (void*)&hbuf, (void*)&flags,
                     (void*)&Wlin, (void*)&blin, (void*)&out };
    hipLaunchCooperativeKernel((const void*)k_lstm_rec, dim3(NBLK), dim3(256),
                               args, 139520, stream);
}

// Round 5
// 14854.550 us; speedup vs baseline: 7.0360x; 7.0360x over previous
//
#include <hip/hip_runtime.h>

typedef __attribute__((ext_vector_type(8))) short short8;
typedef __attribute__((ext_vector_type(4))) float f32x4;
typedef __attribute__((ext_vector_type(4))) unsigned uint32x4;

#define SEQ 4096
#define HID 2048
#define G4  8192
#define NBLK 256

static __device__ __forceinline__ ushort f2bf(float f) {
    unsigned u = __float_as_uint(f);
    u = (u + 0x7fffu + ((u >> 16) & 1u)) >> 16;   // RNE
    return (ushort)u;
}

// Publish one {f32 h, u32 tag} u64 at the device coherence point. Fire-and-
// forget atomic swap: coherent by construction (RMWs execute at the common
// point), no cache-maintenance side effects.
static __device__ __forceinline__ void atomic_pub_u64(unsigned long long* p,
                                                      unsigned long long v) {
    unsigned long long ap = (unsigned long long)p;
    asm volatile("global_atomic_swap_x2 %0, %1, off" :: "v"(ap), "v"(v) : "memory");
}

// 32 B coherent read (two dwordx4, sc0 sc1 = bypass local caches), one waitcnt.
static __device__ __forceinline__ void load_slot8(const unsigned long long* p,
                                                  uint32x4& a, uint32x4& b) {
    unsigned long long ap = (unsigned long long)p;
    asm volatile("global_load_dwordx4 %0, %2, off sc0 sc1\n\t"
                 "global_load_dwordx4 %1, %2, off offset:16 sc0 sc1\n\t"
                 "s_waitcnt vmcnt(0)"
                 : "=&v"(a), "=&v"(b) : "v"(ap) : "memory");
}

// ---------------- f32 -> bf16 conversion (vectorized, 4 elems/thread) ----------
__global__ void __launch_bounds__(256) k_f32_to_bf16(const float* __restrict__ in,
                                                     ushort* __restrict__ out, int n4) {
    int i = blockIdx.x * blockDim.x + threadIdx.x;
    if (i < n4) {
        float4 v = ((const float4*)in)[i];
        ushort4 o;
        o.x = f2bf(v.x); o.y = f2bf(v.y); o.z = f2bf(v.z); o.w = f2bf(v.w);
        ((ushort4*)out)[i] = o;
    }
}

// ---------------- xg = x @ W_ih^T + (b_ih + b_hh), bf16 MFMA, 128x128 tile ------
__global__ void __launch_bounds__(256) k_gemm_xg(
    const ushort* __restrict__ A, const ushort* __restrict__ B,
    const float* __restrict__ bih, const float* __restrict__ bhh,
    float* __restrict__ C)
{
    __shared__ ushort Asm[128 * 40];
    __shared__ ushort Bsm[128 * 40];
    const int tid = threadIdx.x;
    const int brow = blockIdx.y * 128;
    const int bcol = blockIdx.x * 128;
    const int w = tid >> 6, l = tid & 63;
    const int wm = w >> 1, wn = w & 1;

    f32x4 acc[4][4] = {};

    for (int k0 = 0; k0 < 2048; k0 += 32) {
        __syncthreads();
        #pragma unroll
        for (int i = 0; i < 2; ++i) {
            int q = tid + i * 256;
            int r = q >> 2, kc = q & 3;
            *(uint4*)((char*)Asm + r * 80 + kc * 16) =
                *(const uint4*)(A + (size_t)(brow + r) * 2048 + k0 + kc * 8);
            *(uint4*)((char*)Bsm + r * 80 + kc * 16) =
                *(const uint4*)(B + (size_t)(bcol + r) * 2048 + k0 + kc * 8);
        }
        __syncthreads();

        short8 af[4], bf[4];
        #pragma unroll
        for (int m = 0; m < 4; ++m)
            af[m] = *(const short8*)((char*)Asm + (wm * 64 + m * 16 + (l & 15)) * 80 + (l >> 4) * 16);
        #pragma unroll
        for (int n = 0; n < 4; ++n)
            bf[n] = *(const short8*)((char*)Bsm + (wn * 64 + n * 16 + (l & 15)) * 80 + (l >> 4) * 16);

        #pragma unroll
        for (int m = 0; m < 4; ++m)
            #pragma unroll
            for (int n = 0; n < 4; ++n)
                acc[m][n] = __builtin_amdgcn_mfma_f32_16x16x32_bf16(af[m], bf[n], acc[m][n], 0, 0, 0);
    }

    const int lr = (l >> 4) * 4, lc = l & 15;
    #pragma unroll
    for (int m = 0; m < 4; ++m)
        #pragma unroll
        for (int n = 0; n < 4; ++n) {
            int col = bcol + wn * 64 + n * 16 + lc;
            float bsum = bih[col] + bhh[col];
            #pragma unroll
            for (int r = 0; r < 4; ++r) {
                int rowg = brow + wm * 64 + m * 16 + lr + r;
                C[(size_t)rowg * 8192 + col] = acc[m][n][r] + bsum;
            }
        }
}

// ---------------- persistent cooperative LSTM recurrence ------------------------
// 256 blocks x 512 threads. Block b owns h[8b..8b+8); W_hh slice (32 rows) in
// LDS. Cross-block h exchange: hslot[j] = u64 {f32 h (lo), u32 tag (hi)}.
// Producer: global_atomic_swap_x2 (coherent RMW, no cache ops). Consumer:
// sc0-sc1 bypass loads; tag==t proves freshness (tag+data same word -> no
// torn/stale-undetected state). No acquire/release, no buffer_inv/wbl2.
__global__ void __launch_bounds__(512, 1) k_lstm_rec(
    const ushort* __restrict__ Whh,          // bf16 [8192][2048]
    const float* __restrict__ xg,            // [4096][8192]
    unsigned long long* __restrict__ hslot,  // [2048] {h,tag}, 0xFF-memset
    const float* __restrict__ Wlin,          // [2048]
    const float* __restrict__ blin,          // [1]
    float* __restrict__ out)                 // [1]
{
    extern __shared__ char smem[];
    ushort* w_lds = (ushort*)smem;                    // 32*2048*2 = 131072 B
    float*  h_lds = (float*)(smem + 131072);          // 2080 f32  =   8320 B
    float*  g_lds = (float*)(smem + 131072 + 8320);   // 32 f32

    const int tid = threadIdx.x;
    const int b   = blockIdx.x;
    const int hbase = b * 8;

    // stage W_hh rows (once): local row r = gate*8 + kk; 2 rows per pass
    for (int rr = 0; rr < 32; rr += 2) {
        int r = rr + (tid >> 8);
        int e = tid & 255;                 // 256 uint4 per row
        int grow = ((r >> 3) << 11) + hbase + (r & 7);
        ((uint4*)(w_lds + r * 2048))[e] = ((const uint4*)(Whh + (size_t)grow * 2048))[e];
    }

    float c_reg = 0.0f;

    // publish h_0 = 0 with tag 0
    if (tid < 8)
        atomic_pub_u64(&hslot[hbase + tid], 0ull);

    const int row = tid >> 4;   // 0..31 (gate = row>>3, kk = row&7)
    const int cc  = tid & 15;   // 16 col-chunk lanes per row

    for (int t = 0; t < SEQ; ++t) {
        // xg prefetch (independent of h) before the poll
        float xgv0 = 0.f, xgv1 = 0.f, xgv2 = 0.f, xgv3 = 0.f;
        if (tid < 8) {
            const float* xr = xg + (size_t)t * G4 + hbase + tid;
            xgv0 = xr[0]; xgv1 = xr[2048]; xgv2 = xr[4096]; xgv3 = xr[6144];
        }

        // poll own 4 slots until all tags == t, then stage h into LDS
        {
            const unsigned tgt = (unsigned)t;
            uint32x4 a, bq;
            int spin = 0;
            while (true) {
                load_slot8(hslot + tid * 4, a, bq);
                if (a.y == tgt && a.w == tgt && bq.y == tgt && bq.w == tgt) break;
                if ((++spin & 63) == 0) {
                    // escape hatch: proven acquire (emits inv) in case sc0sc1
                    // loads are ever served stale; never taken on the fast path
                    unsigned d = __hip_atomic_load((const unsigned*)hslot,
                                                   __ATOMIC_ACQUIRE, __HIP_MEMORY_SCOPE_AGENT);
                    asm volatile("" :: "v"(d));
                } else {
                    __builtin_amdgcn_s_sleep(2);
                }
            }
            int col = tid * 4;
            *(f32x4*)(h_lds + col + ((col >> 8) << 2)) =
                (f32x4){__uint_as_float(a.x), __uint_as_float(a.z),
                        __uint_as_float(bq.x), __uint_as_float(bq.z)};
        }
        __syncthreads();   // [A]

        // dot: row over cols cc*8 + k*128, W from LDS, h from LDS (f32)
        float s0 = 0.f, s1 = 0.f, s2 = 0.f, s3 = 0.f;
        const ushort* wrow = w_lds + row * 2048;
        #pragma unroll
        for (int k = 0; k < 16; ++k) {
            int col0 = (cc << 3) + (k << 7);
            uint4 wv = *(const uint4*)(wrow + col0);
            const float* hp = h_lds + col0 + ((col0 >> 8) << 2);
            float4 ha = *(const float4*)hp;
            float4 hb = *(const float4*)(hp + 4);
            s0 += __uint_as_float(wv.x << 16)         * ha.x;
            s1 += __uint_as_float(wv.x & 0xffff0000u) * ha.y;
            s2 += __uint_as_float(wv.y << 16)         * ha.z;
            s3 += __uint_as_float(wv.y & 0xffff0000u) * ha.w;
            s0 += __uint_as_float(wv.z << 16)         * hb.x;
            s1 += __uint_as_float(wv.z & 0xffff0000u) * hb.y;
            s2 += __uint_as_float(wv.w << 16)         * hb.z;
            s3 += __uint_as_float(wv.w & 0xffff0000u) * hb.w;
        }
        float sum = (s0 + s1) + (s2 + s3);
        sum += __shfl_xor(sum, 1);
        sum += __shfl_xor(sum, 2);
        sum += __shfl_xor(sum, 4);
        sum += __shfl_xor(sum, 8);
        if (cc == 0) g_lds[row] = sum;
        __syncthreads();   // [B]

        // gates on lanes 0..7; c in registers; publish {h, tag=t+1} atomically
        if (tid < 8) {
            float gi = g_lds[tid]      + xgv0;
            float gf = g_lds[8 + tid]  + xgv1;
            float gg = g_lds[16 + tid] + xgv2;
            float go = g_lds[24 + tid] + xgv3;
            float si = 1.0f / (1.0f + __expf(-gi));
            float sf = 1.0f / (1.0f + __expf(-gf));
            float tg = tanhf(gg);
            float so = 1.0f / (1.0f + __expf(-go));
            c_reg = sf * c_reg + si * tg;
            float hn = so * tanhf(c_reg);
            unsigned long long pv =
                ((unsigned long long)(unsigned)(t + 1) << 32) |
                (unsigned long long)__float_as_uint(hn);
            atomic_pub_u64(&hslot[hbase + tid], pv);
        }
        // no fence needed: tag travels with data in one atomic word
    }

    // final: out = sigmoid(h_SEQ . W_lin + b_lin), block 0 only
    if (b == 0) {
        const unsigned tgt = (unsigned)SEQ;
        uint32x4 a, bq;
        int spin = 0;
        while (true) {
            load_slot8(hslot + tid * 4, a, bq);
            if (a.y == tgt && a.w == tgt && bq.y == tgt && bq.w == tgt) break;
            if ((++spin & 63) == 0) {
                unsigned d = __hip_atomic_load((const unsigned*)hslot,
                                               __ATOMIC_ACQUIRE, __HIP_MEMORY_SCOPE_AGENT);
                asm volatile("" :: "v"(d));
            } else {
                __builtin_amdgcn_s_sleep(2);
            }
        }
        const float* wl = Wlin + tid * 4;
        float s = __uint_as_float(a.x)  * wl[0] + __uint_as_float(a.z)  * wl[1]
                + __uint_as_float(bq.x) * wl[2] + __uint_as_float(bq.z) * wl[3];
        #pragma unroll
        for (int o = 1; o < 64; o <<= 1) s += __shfl_xor(s, o);
        if ((tid & 63) == 0) g_lds[tid >> 6] = s;
        __syncthreads();
        if (tid == 0) {
            float tot = g_lds[0] + g_lds[1] + g_lds[2] + g_lds[3]
                      + g_lds[4] + g_lds[5] + g_lds[6] + g_lds[7] + blin[0];
            out[0] = 1.0f / (1.0f + __expf(-tot));
        }
    }
}

extern "C" void kernel_launch(void* const* d_in, const int* in_sizes, int n_in,
                              void* d_out, int out_size, void* d_ws, size_t ws_size,
                              hipStream_t stream) {
    const float* x    = (const float*)d_in[0];   // [1][4096][2048]
    const float* Wih  = (const float*)d_in[1];   // [8192][2048]
    const float* Whh  = (const float*)d_in[2];   // [8192][2048]
    const float* bih  = (const float*)d_in[3];   // [8192]
    const float* bhh  = (const float*)d_in[4];   // [8192]
    const float* Wlin = (const float*)d_in[5];   // [1][2048]
    const float* blin = (const float*)d_in[6];   // [1]
    float* out = (float*)d_out;

    char* ws = (char*)d_ws;
    float*              xgbuf = (float*)ws;                        // 134,217,728 B
    ushort*             xbf   = (ushort*)(ws + 134217728);         //  16,777,216 B
    ushort*             wihbf = (ushort*)(ws + 150994944);         //  33,554,432 B
    ushort*             whhbf = (ushort*)(ws + 184549376);         //  33,554,432 B
    unsigned long long* hslot = (unsigned long long*)(ws + 218103808); // 16,384 B

    // f32 -> bf16 (x, W_ih, W_hh)
    k_f32_to_bf16<<<8192,  256, 0, stream>>>(x,   xbf,   2097152);
    k_f32_to_bf16<<<16384, 256, 0, stream>>>(Wih, wihbf, 4194304);
    k_f32_to_bf16<<<16384, 256, 0, stream>>>(Whh, whhbf, 4194304);

    // input GEMM: all timesteps' input-side gate preactivations
    k_gemm_xg<<<dim3(64, 32), 256, 0, stream>>>(xbf, wihbf, bih, bhh, xgbuf);

    // invalidate all slot tags every call (tags 0..SEQ can never match 0xFF..)
    hipMemsetAsync(hslot, 0xFF, HID * sizeof(unsigned long long), stream);

    // persistent cooperative recurrence: 139,520 B dynamic LDS, 512 thr/block
    hipFuncSetAttribute((const void*)k_lstm_rec,
                        hipFuncAttributeMaxDynamicSharedMemorySize, 163840);
    void* args[] = { (void*)&whhbf, (void*)&xgbuf, (void*)&hslot,
                     (void*)&Wlin, (void*)&blin, (void*)&out };
    hipLaunchCooperativeKernel((const void*)k_lstm_rec, dim3(NBLK), dim3(512),
                               args, 139520, stream);
}